// Round 17
// baseline (121.722 us; speedup 1.0000x reference)
//
#include <hip/hip_runtime.h>
#include <math.h>

namespace {

constexpr int D = 256;
constexpr int H = 8;

typedef __attribute__((ext_vector_type(8))) short bf16x8;
typedef __attribute__((ext_vector_type(4))) float f32x4;

__device__ inline unsigned short bf16rn(float x) {
  unsigned u = __builtin_bit_cast(unsigned, x);
  u += 0x7fffu + ((u >> 16) & 1u);
  return (unsigned short)(u >> 16);
}
__device__ inline float bf16tof(unsigned short b) {
  return __builtin_bit_cast(float, (unsigned)b << 16);
}

// workspace byte offsets
constexpr size_t OFF_QW  = 0;                          // 8 MiB f32 qW
constexpr size_t OFF_WFH = (size_t)8 << 20;            // 1 MiB W-frag hi
constexpr size_t OFF_WFL = (size_t)9 << 20;            // 1 MiB W-frag lo
constexpr size_t OFF_QFH = (size_t)10 << 20;           // 512 KiB q-frag hi
constexpr size_t OFF_QFL = ((size_t)10 << 20) + ((size_t)512 << 10);

// ---------------- Kernel 0: prep — bf16 hi/lo fragments of q and W ----------------
// (byte-identical to R11-R16 — verified)
__global__ __launch_bounds__(256) void prep_kernel(
    const float* __restrict__ q, const float* __restrict__ W,
    char* __restrict__ ws) {
  const int gid = blockIdx.x * 256 + threadIdx.x;
  float e[8];
  char *hi_base, *lo_base;
  size_t outoff;
  if (gid < 65536) {          // blocks 0..255: W part
    const int l = gid & 63, ks = (gid >> 6) & 7, he = gid >> 9;
    const int h = he >> 4, et = he & 15;
    const int d0 = ks * 32 + ((l >> 4) << 3);
    const int ecol = et * 16 + (l & 15);
    const float* src = W + (size_t)h * 65536 + (size_t)d0 * 256 + ecol;
    #pragma unroll
    for (int j = 0; j < 8; ++j) e[j] = src[j * 256];
    hi_base = ws + OFF_WFH; lo_base = ws + OFF_WFL;
    outoff = (size_t)gid * 16;
  } else {                    // blocks 256..383: q part
    const int t = gid - 65536;
    const int l = t & 63, ks = (t >> 6) & 7, bt = t >> 9;
    const int row = bt * 16 + (l & 15);
    const int d0 = ks * 32 + ((l >> 4) << 3);
    const float4* src = reinterpret_cast<const float4*>(q + (size_t)row * 256 + d0);
    float4 a = src[0], b = src[1];
    e[0] = a.x; e[1] = a.y; e[2] = a.z; e[3] = a.w;
    e[4] = b.x; e[5] = b.y; e[6] = b.z; e[7] = b.w;
    hi_base = ws + OFF_QFH; lo_base = ws + OFF_QFL;
    outoff = (size_t)t * 16;
  }
  unsigned hw[4], lw[4];
  #pragma unroll
  for (int p = 0; p < 4; ++p) {
    unsigned short h0 = bf16rn(e[2 * p]), h1 = bf16rn(e[2 * p + 1]);
    unsigned short l0 = bf16rn(e[2 * p] - bf16tof(h0));
    unsigned short l1 = bf16rn(e[2 * p + 1] - bf16tof(h1));
    hw[p] = (unsigned)h0 | ((unsigned)h1 << 16);
    lw[p] = (unsigned)l0 | ((unsigned)l1 << 16);
  }
  *reinterpret_cast<uint4*>(hi_base + outoff) = make_uint4(hw[0], hw[1], hw[2], hw[3]);
  *reinterpret_cast<uint4*>(lo_base + outoff) = make_uint4(lw[0], lw[1], lw[2], lw[3]);
}

// ---------------- Kernel 1: qW via split-bf16 MFMA ----------------
// (byte-identical to R11-R16 — verified; keeps f32-grade qW)
__global__ __launch_bounds__(256) void qw_mfma_kernel(
    const char* __restrict__ ws_in, float* __restrict__ qW) {
  const int tid = threadIdx.x;
  const int w   = blockIdx.x * 4 + (tid >> 6);
  const int l   = tid & 63;
  const int bng = w >> 5;
  const int heg = w & 31;
  const char* qfh = ws_in + OFF_QFH;
  const char* qfl = ws_in + OFF_QFL;
  const char* wfh = ws_in + OFF_WFH;
  const char* wfl = ws_in + OFF_WFL;

  f32x4 acc[2][4];
  #pragma unroll
  for (int i = 0; i < 2; ++i)
    #pragma unroll
    for (int j = 0; j < 4; ++j) acc[i][j] = {0.f, 0.f, 0.f, 0.f};

  #pragma unroll 2
  for (int ks = 0; ks < 8; ++ks) {
    bf16x8 aH[2], aL[2], bH[4], bL[4];
    #pragma unroll
    for (int i = 0; i < 2; ++i) {
      const size_t off = ((size_t)((bng * 2 + i) * 8 + ks) * 64 + l) * 16;
      aH[i] = *reinterpret_cast<const bf16x8*>(qfh + off);
      aL[i] = *reinterpret_cast<const bf16x8*>(qfl + off);
    }
    #pragma unroll
    for (int j = 0; j < 4; ++j) {
      const size_t off = ((size_t)((heg * 4 + j) * 8 + ks) * 64 + l) * 16;
      bH[j] = *reinterpret_cast<const bf16x8*>(wfh + off);
      bL[j] = *reinterpret_cast<const bf16x8*>(wfl + off);
    }
    #pragma unroll
    for (int i = 0; i < 2; ++i)
      #pragma unroll
      for (int j = 0; j < 4; ++j) {
        acc[i][j] = __builtin_amdgcn_mfma_f32_16x16x32_bf16(aH[i], bH[j], acc[i][j], 0, 0, 0);
        acc[i][j] = __builtin_amdgcn_mfma_f32_16x16x32_bf16(aH[i], bL[j], acc[i][j], 0, 0, 0);
        acc[i][j] = __builtin_amdgcn_mfma_f32_16x16x32_bf16(aL[i], bH[j], acc[i][j], 0, 0, 0);
      }
  }

  const int rbase = (l >> 4) * 4;
  const int col   = l & 15;
  #pragma unroll
  for (int i = 0; i < 2; ++i)
    #pragma unroll
    for (int j = 0; j < 4; ++j) {
      const size_t cidx = (size_t)(heg * 4 + j) * 16 + col;
      #pragma unroll
      for (int r = 0; r < 4; ++r) {
        const int bn = (bng * 2 + i) * 16 + rbase + r;
        qW[(size_t)bn * 2048 + cidx] = acc[i][j][r];
      }
    }
}

// ---------------- Kernel 2: fused scores+softmax+PV — 8 waves/bn (32 waves/CU) ----
// Per-bn block, 512 thr = 8 waves; 1024 blocks x 8 = 32 waves/CU (launch_bounds
// (512,8) -> VGPR<=64). Waves 0-3: R16-verified score machinery (tile T=wid:
// A-direct k-frag loads, MFMA, chunk softmax, attn write, wsp). Waves 4-7: PV
// streamers — issue 16 v-row loads at t=0 (in flight under the whole score
// phase), multiply by wsum after the barrier. Role split doubles resident waves
// and halves each wave's load burden — TLP does the latency hiding (pv_kernel
// evidence: this shape delivered ~4.9 TB/s in R4/R5).
constexpr int FB2   = 0;
constexpr int WSP2  = 8320;
constexpr int SMEM3 = 9344;

__global__ __launch_bounds__(512, 8) void attn_fused_kernel(
    const float* __restrict__ qW, const float* __restrict__ kin,
    const float* __restrict__ vin, const float* __restrict__ bin,
    float* __restrict__ out, float* __restrict__ attn_out) {
  __shared__ alignas(16) long long smem_ll[SMEM3 / 8];
  char* sm = reinterpret_cast<char*>(smem_ll);
  float* wsp = reinterpret_cast<float*>(sm + WSP2);   // flat [4*64]
  const int tid = threadIdx.x;
  const int bn  = blockIdx.x;
  const int wid = tid >> 6;          // 0..7
  const int ln  = tid & 63;
  const bool is_score = wid < 4;

  // ---- per-role global load issue (wave-uniform branch; all waves issue at t=0)
  float4 ka[16];                     // score waves: A-direct k-frags
  float4 vv[16];                     // pv waves: v rows (wid-4) + 4i
  if (is_score) {
    const float* arow = kin + (size_t)bn * 16384 +
                        (size_t)(wid * 16 + (ln & 15)) * 256 + ((ln >> 4) << 3);
    #pragma unroll
    for (int ks = 0; ks < 8; ++ks) {
      ka[2 * ks]     = *reinterpret_cast<const float4*>(arow + ks * 32);
      ka[2 * ks + 1] = *reinterpret_cast<const float4*>(arow + ks * 32 + 4);
    }
  } else {
    const float4* v4 = reinterpret_cast<const float4*>(vin) + (size_t)bn * 4096;
    #pragma unroll
    for (int i = 0; i < 16; ++i)
      vv[i] = v4[(size_t)((wid - 4) + 4 * i) * 64 + ln];
  }

  // ---- qW stage: 512 threads x 1 float4 = full 8x256 row
  const float4* qw4 = reinterpret_cast<const float4*>(qW) + (size_t)bn * 512;
  float4 qv = qw4[tid];

  // ---- zero-fill unwritten B slots (cols 8-15): 256 slots, first 256 threads
  if (tid < 256) {
    const int ks = tid >> 5, slot = 32 + (tid & 31);
    *reinterpret_cast<uint4*>(sm + FB2 + ks * 1040 + slot * 16) =
        make_uint4(0u, 0u, 0u, 0u);
  }
  // ---- qW -> B-hi frags (R13-R16-verified placement); p = tid covers 0..511
  {
    const int hh = tid >> 6, equad = tid & 63;
    const int ks = equad >> 3, g = (equad >> 1) & 3, j0 = (equad & 1) * 4;
    const int base = FB2 + ks * 1040 + (hh * 4 + g) * 16 + j0 * 2;
    unsigned short h0 = bf16rn(qv.x), h1 = bf16rn(qv.y),
                   h2 = bf16rn(qv.z), h3 = bf16rn(qv.w);
    *reinterpret_cast<uint2*>(sm + base) =
        make_uint2((unsigned)h0 | ((unsigned)h1 << 16),
                   (unsigned)h2 | ((unsigned)h3 << 16));
  }
  __syncthreads();   // B1: B-frags visible

  if (is_score) {
    // ---- MFMA over full K=256, tile T = wid (converts ka in registers)
    const int slot_r = (ln & 15) * 4 + (ln >> 4);
    const char* pbH = sm + FB2 + slot_r * 16;
    f32x4 acc = {0.f, 0.f, 0.f, 0.f};
    #pragma unroll
    for (int ks = 0; ks < 8; ++ks) {
      const float4 a0 = ka[2 * ks], a1 = ka[2 * ks + 1];
      bf16x8 aH;
      aH[0] = (short)bf16rn(a0.x); aH[1] = (short)bf16rn(a0.y);
      aH[2] = (short)bf16rn(a0.z); aH[3] = (short)bf16rn(a0.w);
      aH[4] = (short)bf16rn(a1.x); aH[5] = (short)bf16rn(a1.y);
      aH[6] = (short)bf16rn(a1.z); aH[7] = (short)bf16rn(a1.w);
      bf16x8 bH = *reinterpret_cast<const bf16x8*>(pbH + ks * 1040);
      acc = __builtin_amdgcn_mfma_f32_16x16x32_bf16(aH, bH, acc, 0, 0, 0);
    }

    // ---- softmax on C-frags (chunk = 2*wid + (ln>=32); R14-R16-verified)
    const float bias = bin[ln & 7];
    const int col = ln & 15;
    const bool valid = col < 8;
    float x0 = acc[0] + bias, x1 = acc[1] + bias, x2 = acc[2] + bias, x3 = acc[3] + bias;
    float m = valid ? fmaxf(fmaxf(x0, x1), fmaxf(x2, x3)) : -1e30f;
    m = fmaxf(m, __shfl_xor(m, 1, 64));
    m = fmaxf(m, __shfl_xor(m, 2, 64));
    m = fmaxf(m, __shfl_xor(m, 4, 64));
    m = fmaxf(m, __shfl_xor(m, 16, 64));
    float e0 = valid ? expf(x0 - m) : 0.f;
    float e1 = valid ? expf(x1 - m) : 0.f;
    float e2 = valid ? expf(x2 - m) : 0.f;
    float e3 = valid ? expf(x3 - m) : 0.f;
    float s = e0 + e1 + e2 + e3;
    s += __shfl_xor(s, 1, 64);
    s += __shfl_xor(s, 2, 64);
    s += __shfl_xor(s, 4, 64);
    s += __shfl_xor(s, 16, 64);
    float inv = 1.f / s;
    float p0 = e0 * inv, p1 = e1 * inv, p2 = e2 * inv, p3 = e3 * inv;
    if (valid) {
      size_t base = (size_t)bn * 512 + (size_t)(wid * 16 + (ln >> 4) * 4) * 8 + col;
      attn_out[base]      = p0;
      attn_out[base + 8]  = p1;
      attn_out[base + 16] = p2;
      attn_out[base + 24] = p3;
    }
    // wsum partial: pos=(row&7)*8+col, chunk-pair sum via xor-32; one writer/pos.
    p0 += __shfl_xor(p0, 32, 64);
    p1 += __shfl_xor(p1, 32, 64);
    p2 += __shfl_xor(p2, 32, 64);
    p3 += __shfl_xor(p3, 32, 64);
    if (ln < 32 && (ln & 15) < 8) {
      const int rb = (ln >> 4) * 4;
      const int c8 = ln & 7;
      float* w = wsp + wid * 64;
      w[(rb + 0) * 8 + c8] = p0;
      w[(rb + 1) * 8 + c8] = p1;
      w[(rb + 2) * 8 + c8] = p2;
      w[(rb + 3) * 8 + c8] = p3;
    }
  }
  __syncthreads();   // B2: wsp complete; B-frag area dead below

  float* s_red = reinterpret_cast<float*>(sm);   // [4][260] alias on dead B-frag area
  if (!is_score) {
    // ---- PV from pre-loaded vv; wsum via broadcast LDS reads
    float4 av = make_float4(0.f, 0.f, 0.f, 0.f);
    #pragma unroll
    for (int i = 0; i < 16; ++i) {
      const int r = (wid - 4) + 4 * i;
      float w = wsp[r] + wsp[64 + r] + wsp[128 + r] + wsp[192 + r];
      av.x += w * vv[i].x; av.y += w * vv[i].y;
      av.z += w * vv[i].z; av.w += w * vv[i].w;
    }
    *reinterpret_cast<float4*>(&s_red[(wid - 4) * 260 + (ln << 2)]) = av;
  }
  __syncthreads();   // B3: s_red complete

  if (tid < 256) {
    out[(size_t)bn * D + tid] =
        s_red[tid] + s_red[260 + tid] + s_red[520 + tid] + s_red[780 + tid];
  }
}

}  // namespace

extern "C" void kernel_launch(void* const* d_in, const int* in_sizes, int n_in,
                              void* d_out, int out_size, void* d_ws, size_t ws_size,
                              hipStream_t stream) {
  const float* q = (const float*)d_in[0];   // (8,128,1,256)
  const float* k = (const float*)d_in[1];   // (8,128,64,256)
  const float* v = (const float*)d_in[2];   // (8,128,64,256)
  const float* W = (const float*)d_in[3];   // (8,256,256)
  const float* b = (const float*)d_in[4];   // (8,)

  float* out  = (float*)d_out;              // output: 262144 f32
  float* attn = out + 262144;               // attn:   524288 f32
  char*  ws   = (char*)d_ws;
  float* qWbuf = (float*)(ws + OFF_QW);     // 8 MiB f32 qW

  hipLaunchKernelGGL(prep_kernel,       dim3(384),  dim3(256), 0, stream, q, W, ws);
  hipLaunchKernelGGL(qw_mfma_kernel,    dim3(256),  dim3(256), 0, stream, ws, qWbuf);
  hipLaunchKernelGGL(attn_fused_kernel, dim3(1024), dim3(512), 0, stream,
                     qWbuf, k, v, b, out, attn);
}

// Round 18
// 44.537 us; speedup vs baseline: 2.7330x; 2.7330x over previous
//
#include <hip/hip_runtime.h>
#include <math.h>

namespace {

constexpr int D = 256;
constexpr int H = 8;

typedef __attribute__((ext_vector_type(8))) short bf16x8;
typedef __attribute__((ext_vector_type(4))) float f32x4;

__device__ inline unsigned short bf16rn(float x) {
  unsigned u = __builtin_bit_cast(unsigned, x);
  u += 0x7fffu + ((u >> 16) & 1u);
  return (unsigned short)(u >> 16);
}
__device__ inline float bf16tof(unsigned short b) {
  return __builtin_bit_cast(float, (unsigned)b << 16);
}

// workspace byte offsets
constexpr size_t OFF_QW  = 0;                          // 8 MiB f32 qW
constexpr size_t OFF_WFH = (size_t)8 << 20;            // 1 MiB W-frag hi
constexpr size_t OFF_WFL = (size_t)9 << 20;            // 1 MiB W-frag lo
constexpr size_t OFF_QFH = (size_t)10 << 20;           // 512 KiB q-frag hi
constexpr size_t OFF_QFL = ((size_t)10 << 20) + ((size_t)512 << 10);

// ---------------- Kernel 0: prep — bf16 hi/lo fragments of q and W ----------------
// (byte-identical to R11-R17 — verified)
__global__ __launch_bounds__(256) void prep_kernel(
    const float* __restrict__ q, const float* __restrict__ W,
    char* __restrict__ ws) {
  const int gid = blockIdx.x * 256 + threadIdx.x;
  float e[8];
  char *hi_base, *lo_base;
  size_t outoff;
  if (gid < 65536) {          // blocks 0..255: W part
    const int l = gid & 63, ks = (gid >> 6) & 7, he = gid >> 9;
    const int h = he >> 4, et = he & 15;
    const int d0 = ks * 32 + ((l >> 4) << 3);
    const int ecol = et * 16 + (l & 15);
    const float* src = W + (size_t)h * 65536 + (size_t)d0 * 256 + ecol;
    #pragma unroll
    for (int j = 0; j < 8; ++j) e[j] = src[j * 256];
    hi_base = ws + OFF_WFH; lo_base = ws + OFF_WFL;
    outoff = (size_t)gid * 16;
  } else {                    // blocks 256..383: q part
    const int t = gid - 65536;
    const int l = t & 63, ks = (t >> 6) & 7, bt = t >> 9;
    const int row = bt * 16 + (l & 15);
    const int d0 = ks * 32 + ((l >> 4) << 3);
    const float4* src = reinterpret_cast<const float4*>(q + (size_t)row * 256 + d0);
    float4 a = src[0], b = src[1];
    e[0] = a.x; e[1] = a.y; e[2] = a.z; e[3] = a.w;
    e[4] = b.x; e[5] = b.y; e[6] = b.z; e[7] = b.w;
    hi_base = ws + OFF_QFH; lo_base = ws + OFF_QFL;
    outoff = (size_t)t * 16;
  }
  unsigned hw[4], lw[4];
  #pragma unroll
  for (int p = 0; p < 4; ++p) {
    unsigned short h0 = bf16rn(e[2 * p]), h1 = bf16rn(e[2 * p + 1]);
    unsigned short l0 = bf16rn(e[2 * p] - bf16tof(h0));
    unsigned short l1 = bf16rn(e[2 * p + 1] - bf16tof(h1));
    hw[p] = (unsigned)h0 | ((unsigned)h1 << 16);
    lw[p] = (unsigned)l0 | ((unsigned)l1 << 16);
  }
  *reinterpret_cast<uint4*>(hi_base + outoff) = make_uint4(hw[0], hw[1], hw[2], hw[3]);
  *reinterpret_cast<uint4*>(lo_base + outoff) = make_uint4(lw[0], lw[1], lw[2], lw[3]);
}

// ---------------- Kernel 1: qW via split-bf16 MFMA ----------------
// (byte-identical to R11-R17 — verified; keeps f32-grade qW)
__global__ __launch_bounds__(256) void qw_mfma_kernel(
    const char* __restrict__ ws_in, float* __restrict__ qW) {
  const int tid = threadIdx.x;
  const int w   = blockIdx.x * 4 + (tid >> 6);
  const int l   = tid & 63;
  const int bng = w >> 5;
  const int heg = w & 31;
  const char* qfh = ws_in + OFF_QFH;
  const char* qfl = ws_in + OFF_QFL;
  const char* wfh = ws_in + OFF_WFH;
  const char* wfl = ws_in + OFF_WFL;

  f32x4 acc[2][4];
  #pragma unroll
  for (int i = 0; i < 2; ++i)
    #pragma unroll
    for (int j = 0; j < 4; ++j) acc[i][j] = {0.f, 0.f, 0.f, 0.f};

  #pragma unroll 2
  for (int ks = 0; ks < 8; ++ks) {
    bf16x8 aH[2], aL[2], bH[4], bL[4];
    #pragma unroll
    for (int i = 0; i < 2; ++i) {
      const size_t off = ((size_t)((bng * 2 + i) * 8 + ks) * 64 + l) * 16;
      aH[i] = *reinterpret_cast<const bf16x8*>(qfh + off);
      aL[i] = *reinterpret_cast<const bf16x8*>(qfl + off);
    }
    #pragma unroll
    for (int j = 0; j < 4; ++j) {
      const size_t off = ((size_t)((heg * 4 + j) * 8 + ks) * 64 + l) * 16;
      bH[j] = *reinterpret_cast<const bf16x8*>(wfh + off);
      bL[j] = *reinterpret_cast<const bf16x8*>(wfl + off);
    }
    #pragma unroll
    for (int i = 0; i < 2; ++i)
      #pragma unroll
      for (int j = 0; j < 4; ++j) {
        acc[i][j] = __builtin_amdgcn_mfma_f32_16x16x32_bf16(aH[i], bH[j], acc[i][j], 0, 0, 0);
        acc[i][j] = __builtin_amdgcn_mfma_f32_16x16x32_bf16(aH[i], bL[j], acc[i][j], 0, 0, 0);
        acc[i][j] = __builtin_amdgcn_mfma_f32_16x16x32_bf16(aL[i], bH[j], acc[i][j], 0, 0, 0);
      }
  }

  const int rbase = (l >> 4) * 4;
  const int col   = l & 15;
  #pragma unroll
  for (int i = 0; i < 2; ++i)
    #pragma unroll
    for (int j = 0; j < 4; ++j) {
      const size_t cidx = (size_t)(heg * 4 + j) * 16 + col;
      #pragma unroll
      for (int r = 0; r < 4; ++r) {
        const int bn = (bng * 2 + i) * 16 + rbase + r;
        qW[(size_t)bn * 2048 + cidx] = acc[i][j][r];
      }
    }
}

// ---------------- Kernel 2: fused — 8 waves/bn, split roles, rolling windows ------
// Per-bn block, 512 thr = 8 waves, launch_bounds(512,6) -> 85-VGPR budget,
// 3 blocks/CU = 24 waves/CU. Waves 0-3: score tile T=wid — 2-float4 rolling
// k window (load ks+1 under MFMA of ks; fully unrolled -> static SSA, no spill).
// Waves 4-7: PV — 4-float4 ping-pong v window; batch 0 issued at t=0 rides under
// the whole score phase. R17 lesson: (512,8) spilled ka/vv to scratch (318 MB
// writes); small windows + 85-reg budget keep everything in registers.
constexpr int FB2   = 0;
constexpr int WSP2  = 8320;
constexpr int SMEM3 = 9344;

__global__ __launch_bounds__(512, 6) void attn_fused_kernel(
    const float* __restrict__ qW, const float* __restrict__ kin,
    const float* __restrict__ vin, const float* __restrict__ bin,
    float* __restrict__ out, float* __restrict__ attn_out) {
  __shared__ alignas(16) long long smem_ll[SMEM3 / 8];
  char* sm = reinterpret_cast<char*>(smem_ll);
  float* wsp = reinterpret_cast<float*>(sm + WSP2);   // flat [4*64]
  const int tid = threadIdx.x;
  const int bn  = blockIdx.x;
  const int wid = tid >> 6;          // 0..7
  const int ln  = tid & 63;
  const bool is_score = wid < 4;

  const float4* v4 = reinterpret_cast<const float4*>(vin) + (size_t)bn * 4096;
  const int pvrow0 = (wid - 4);      // pv row stride 4: r = pvrow0 + 4*i

  // ---- early prefetches (t=0): score ks0 window / pv batch 0
  const float* arow = kin + (size_t)bn * 16384 +
                      (size_t)((wid & 3) * 16 + (ln & 15)) * 256 + ((ln >> 4) << 3);
  float4 kc0, kc1;                   // score: current ks window
  float4 vA0, vA1, vA2, vA3;         // pv: current 4-row batch
  if (is_score) {
    kc0 = *reinterpret_cast<const float4*>(arow);
    kc1 = *reinterpret_cast<const float4*>(arow + 4);
  } else {
    vA0 = v4[(size_t)(pvrow0 + 4 * 0) * 64 + ln];
    vA1 = v4[(size_t)(pvrow0 + 4 * 1) * 64 + ln];
    vA2 = v4[(size_t)(pvrow0 + 4 * 2) * 64 + ln];
    vA3 = v4[(size_t)(pvrow0 + 4 * 3) * 64 + ln];
  }

  // ---- qW stage: 512 threads x 1 float4 = full 8x256 row
  const float4* qw4 = reinterpret_cast<const float4*>(qW) + (size_t)bn * 512;
  float4 qv = qw4[tid];

  // ---- zero-fill unwritten B slots (cols 8-15): 256 slots, first 256 threads
  if (tid < 256) {
    const int ks = tid >> 5, slot = 32 + (tid & 31);
    *reinterpret_cast<uint4*>(sm + FB2 + ks * 1040 + slot * 16) =
        make_uint4(0u, 0u, 0u, 0u);
  }
  // ---- qW -> B-hi frags (verified placement); tid covers 0..511
  {
    const int hh = tid >> 6, equad = tid & 63;
    const int ks = equad >> 3, g = (equad >> 1) & 3, j0 = (equad & 1) * 4;
    const int base = FB2 + ks * 1040 + (hh * 4 + g) * 16 + j0 * 2;
    unsigned short h0 = bf16rn(qv.x), h1 = bf16rn(qv.y),
                   h2 = bf16rn(qv.z), h3 = bf16rn(qv.w);
    *reinterpret_cast<uint2*>(sm + base) =
        make_uint2((unsigned)h0 | ((unsigned)h1 << 16),
                   (unsigned)h2 | ((unsigned)h3 << 16));
  }
  __syncthreads();   // B1: B-frags visible

  if (is_score) {
    // ---- MFMA with rolling 2-float4 k window (unrolled -> static)
    const int slot_r = (ln & 15) * 4 + (ln >> 4);
    const char* pbH = sm + FB2 + slot_r * 16;
    f32x4 acc = {0.f, 0.f, 0.f, 0.f};
    #pragma unroll
    for (int ks = 0; ks < 8; ++ks) {
      float4 kn0, kn1;
      if (ks < 7) {
        kn0 = *reinterpret_cast<const float4*>(arow + (ks + 1) * 32);
        kn1 = *reinterpret_cast<const float4*>(arow + (ks + 1) * 32 + 4);
      }
      bf16x8 aH;
      aH[0] = (short)bf16rn(kc0.x); aH[1] = (short)bf16rn(kc0.y);
      aH[2] = (short)bf16rn(kc0.z); aH[3] = (short)bf16rn(kc0.w);
      aH[4] = (short)bf16rn(kc1.x); aH[5] = (short)bf16rn(kc1.y);
      aH[6] = (short)bf16rn(kc1.z); aH[7] = (short)bf16rn(kc1.w);
      bf16x8 bH = *reinterpret_cast<const bf16x8*>(pbH + ks * 1040);
      acc = __builtin_amdgcn_mfma_f32_16x16x32_bf16(aH, bH, acc, 0, 0, 0);
      kc0 = kn0; kc1 = kn1;
    }

    // ---- softmax on C-frags (verified reduce)
    const float bias = bin[ln & 7];
    const int col = ln & 15;
    const bool valid = col < 8;
    float x0 = acc[0] + bias, x1 = acc[1] + bias, x2 = acc[2] + bias, x3 = acc[3] + bias;
    float m = valid ? fmaxf(fmaxf(x0, x1), fmaxf(x2, x3)) : -1e30f;
    m = fmaxf(m, __shfl_xor(m, 1, 64));
    m = fmaxf(m, __shfl_xor(m, 2, 64));
    m = fmaxf(m, __shfl_xor(m, 4, 64));
    m = fmaxf(m, __shfl_xor(m, 16, 64));
    float e0 = valid ? expf(x0 - m) : 0.f;
    float e1 = valid ? expf(x1 - m) : 0.f;
    float e2 = valid ? expf(x2 - m) : 0.f;
    float e3 = valid ? expf(x3 - m) : 0.f;
    float s = e0 + e1 + e2 + e3;
    s += __shfl_xor(s, 1, 64);
    s += __shfl_xor(s, 2, 64);
    s += __shfl_xor(s, 4, 64);
    s += __shfl_xor(s, 16, 64);
    float inv = 1.f / s;
    float p0 = e0 * inv, p1 = e1 * inv, p2 = e2 * inv, p3 = e3 * inv;
    if (valid) {
      size_t base = (size_t)bn * 512 + (size_t)(wid * 16 + (ln >> 4) * 4) * 8 + col;
      attn_out[base]      = p0;
      attn_out[base + 8]  = p1;
      attn_out[base + 16] = p2;
      attn_out[base + 24] = p3;
    }
    // wsum partial (verified mapping)
    p0 += __shfl_xor(p0, 32, 64);
    p1 += __shfl_xor(p1, 32, 64);
    p2 += __shfl_xor(p2, 32, 64);
    p3 += __shfl_xor(p3, 32, 64);
    if (ln < 32 && (ln & 15) < 8) {
      const int rb = (ln >> 4) * 4;
      const int c8 = ln & 7;
      float* w = wsp + wid * 64;
      w[(rb + 0) * 8 + c8] = p0;
      w[(rb + 1) * 8 + c8] = p1;
      w[(rb + 2) * 8 + c8] = p2;
      w[(rb + 3) * 8 + c8] = p3;
    }
  }
  __syncthreads();   // B2: wsp complete; B-frag area dead below

  float* s_red = reinterpret_cast<float*>(sm);   // [4][260] alias on dead B-frag area
  if (!is_score) {
    // ---- PV: ping-pong 4-row batches; batch j covers i = 4j..4j+3 (r = pvrow0+4i)
    float4 av = make_float4(0.f, 0.f, 0.f, 0.f);
    #pragma unroll
    for (int bj = 0; bj < 4; ++bj) {
      float4 vB0, vB1, vB2, vB3;
      if (bj < 3) {
        vB0 = v4[(size_t)(pvrow0 + 4 * (4 * bj + 4)) * 64 + ln];
        vB1 = v4[(size_t)(pvrow0 + 4 * (4 * bj + 5)) * 64 + ln];
        vB2 = v4[(size_t)(pvrow0 + 4 * (4 * bj + 6)) * 64 + ln];
        vB3 = v4[(size_t)(pvrow0 + 4 * (4 * bj + 7)) * 64 + ln];
      }
      #pragma unroll
      for (int jj = 0; jj < 4; ++jj) {
        const int r = pvrow0 + 4 * (4 * bj + jj);
        float w = wsp[r] + wsp[64 + r] + wsp[128 + r] + wsp[192 + r];
        const float4 vc = jj == 0 ? vA0 : jj == 1 ? vA1 : jj == 2 ? vA2 : vA3;
        av.x += w * vc.x; av.y += w * vc.y; av.z += w * vc.z; av.w += w * vc.w;
      }
      vA0 = vB0; vA1 = vB1; vA2 = vB2; vA3 = vB3;
    }
    *reinterpret_cast<float4*>(&s_red[(wid - 4) * 260 + (ln << 2)]) = av;
  }
  __syncthreads();   // B3: s_red complete

  if (tid < 256) {
    out[(size_t)bn * D + tid] =
        s_red[tid] + s_red[260 + tid] + s_red[520 + tid] + s_red[780 + tid];
  }
}

}  // namespace

extern "C" void kernel_launch(void* const* d_in, const int* in_sizes, int n_in,
                              void* d_out, int out_size, void* d_ws, size_t ws_size,
                              hipStream_t stream) {
  const float* q = (const float*)d_in[0];   // (8,128,1,256)
  const float* k = (const float*)d_in[1];   // (8,128,64,256)
  const float* v = (const float*)d_in[2];   // (8,128,64,256)
  const float* W = (const float*)d_in[3];   // (8,256,256)
  const float* b = (const float*)d_in[4];   // (8,)

  float* out  = (float*)d_out;              // output: 262144 f32
  float* attn = out + 262144;               // attn:   524288 f32
  char*  ws   = (char*)d_ws;
  float* qWbuf = (float*)(ws + OFF_QW);     // 8 MiB f32 qW

  hipLaunchKernelGGL(prep_kernel,       dim3(384),  dim3(256), 0, stream, q, W, ws);
  hipLaunchKernelGGL(qw_mfma_kernel,    dim3(256),  dim3(256), 0, stream, ws, qWbuf);
  hipLaunchKernelGGL(attn_fused_kernel, dim3(1024), dim3(512), 0, stream,
                     qWbuf, k, v, b, out, attn);
}

// Round 19
// 44.106 us; speedup vs baseline: 2.7598x; 1.0098x over previous
//
#include <hip/hip_runtime.h>
#include <math.h>

namespace {

constexpr int D = 256;
constexpr int H = 8;

typedef __attribute__((ext_vector_type(8))) short bf16x8;
typedef __attribute__((ext_vector_type(4))) float f32x4;

__device__ inline unsigned short bf16rn(float x) {
  unsigned u = __builtin_bit_cast(unsigned, x);
  u += 0x7fffu + ((u >> 16) & 1u);
  return (unsigned short)(u >> 16);
}
__device__ inline float bf16tof(unsigned short b) {
  return __builtin_bit_cast(float, (unsigned)b << 16);
}

// workspace byte offsets
constexpr size_t OFF_QW  = 0;                          // 8 MiB f32 qW
constexpr size_t OFF_WFH = (size_t)8 << 20;            // 1 MiB W-frag hi
constexpr size_t OFF_WFL = (size_t)9 << 20;            // 1 MiB W-frag lo
constexpr size_t OFF_QFH = (size_t)10 << 20;           // 512 KiB q-frag hi
constexpr size_t OFF_QFL = ((size_t)10 << 20) + ((size_t)512 << 10);

// ---------------- Kernel 0: prep — bf16 hi/lo fragments of q and W ----------------
// (byte-identical to R11-R18 — verified)
__global__ __launch_bounds__(256) void prep_kernel(
    const float* __restrict__ q, const float* __restrict__ W,
    char* __restrict__ ws) {
  const int gid = blockIdx.x * 256 + threadIdx.x;
  float e[8];
  char *hi_base, *lo_base;
  size_t outoff;
  if (gid < 65536) {          // blocks 0..255: W part
    const int l = gid & 63, ks = (gid >> 6) & 7, he = gid >> 9;
    const int h = he >> 4, et = he & 15;
    const int d0 = ks * 32 + ((l >> 4) << 3);
    const int ecol = et * 16 + (l & 15);
    const float* src = W + (size_t)h * 65536 + (size_t)d0 * 256 + ecol;
    #pragma unroll
    for (int j = 0; j < 8; ++j) e[j] = src[j * 256];
    hi_base = ws + OFF_WFH; lo_base = ws + OFF_WFL;
    outoff = (size_t)gid * 16;
  } else {                    // blocks 256..383: q part
    const int t = gid - 65536;
    const int l = t & 63, ks = (t >> 6) & 7, bt = t >> 9;
    const int row = bt * 16 + (l & 15);
    const int d0 = ks * 32 + ((l >> 4) << 3);
    const float4* src = reinterpret_cast<const float4*>(q + (size_t)row * 256 + d0);
    float4 a = src[0], b = src[1];
    e[0] = a.x; e[1] = a.y; e[2] = a.z; e[3] = a.w;
    e[4] = b.x; e[5] = b.y; e[6] = b.z; e[7] = b.w;
    hi_base = ws + OFF_QFH; lo_base = ws + OFF_QFL;
    outoff = (size_t)t * 16;
  }
  unsigned hw[4], lw[4];
  #pragma unroll
  for (int p = 0; p < 4; ++p) {
    unsigned short h0 = bf16rn(e[2 * p]), h1 = bf16rn(e[2 * p + 1]);
    unsigned short l0 = bf16rn(e[2 * p] - bf16tof(h0));
    unsigned short l1 = bf16rn(e[2 * p + 1] - bf16tof(h1));
    hw[p] = (unsigned)h0 | ((unsigned)h1 << 16);
    lw[p] = (unsigned)l0 | ((unsigned)l1 << 16);
  }
  *reinterpret_cast<uint4*>(hi_base + outoff) = make_uint4(hw[0], hw[1], hw[2], hw[3]);
  *reinterpret_cast<uint4*>(lo_base + outoff) = make_uint4(lw[0], lw[1], lw[2], lw[3]);
}

// ---------------- Kernel 1: qW via split-bf16 MFMA ----------------
// (byte-identical to R11-R18 — verified; keeps f32-grade qW)
__global__ __launch_bounds__(256) void qw_mfma_kernel(
    const char* __restrict__ ws_in, float* __restrict__ qW) {
  const int tid = threadIdx.x;
  const int w   = blockIdx.x * 4 + (tid >> 6);
  const int l   = tid & 63;
  const int bng = w >> 5;
  const int heg = w & 31;
  const char* qfh = ws_in + OFF_QFH;
  const char* qfl = ws_in + OFF_QFL;
  const char* wfh = ws_in + OFF_WFH;
  const char* wfl = ws_in + OFF_WFL;

  f32x4 acc[2][4];
  #pragma unroll
  for (int i = 0; i < 2; ++i)
    #pragma unroll
    for (int j = 0; j < 4; ++j) acc[i][j] = {0.f, 0.f, 0.f, 0.f};

  #pragma unroll 2
  for (int ks = 0; ks < 8; ++ks) {
    bf16x8 aH[2], aL[2], bH[4], bL[4];
    #pragma unroll
    for (int i = 0; i < 2; ++i) {
      const size_t off = ((size_t)((bng * 2 + i) * 8 + ks) * 64 + l) * 16;
      aH[i] = *reinterpret_cast<const bf16x8*>(qfh + off);
      aL[i] = *reinterpret_cast<const bf16x8*>(qfl + off);
    }
    #pragma unroll
    for (int j = 0; j < 4; ++j) {
      const size_t off = ((size_t)((heg * 4 + j) * 8 + ks) * 64 + l) * 16;
      bH[j] = *reinterpret_cast<const bf16x8*>(wfh + off);
      bL[j] = *reinterpret_cast<const bf16x8*>(wfl + off);
    }
    #pragma unroll
    for (int i = 0; i < 2; ++i)
      #pragma unroll
      for (int j = 0; j < 4; ++j) {
        acc[i][j] = __builtin_amdgcn_mfma_f32_16x16x32_bf16(aH[i], bH[j], acc[i][j], 0, 0, 0);
        acc[i][j] = __builtin_amdgcn_mfma_f32_16x16x32_bf16(aH[i], bL[j], acc[i][j], 0, 0, 0);
        acc[i][j] = __builtin_amdgcn_mfma_f32_16x16x32_bf16(aL[i], bH[j], acc[i][j], 0, 0, 0);
      }
  }

  const int rbase = (l >> 4) * 4;
  const int col   = l & 15;
  #pragma unroll
  for (int i = 0; i < 2; ++i)
    #pragma unroll
    for (int j = 0; j < 4; ++j) {
      const size_t cidx = (size_t)(heg * 4 + j) * 16 + col;
      #pragma unroll
      for (int r = 0; r < 4; ++r) {
        const int bn = (bng * 2 + i) * 16 + rbase + r;
        qW[(size_t)bn * 2048 + cidx] = acc[i][j][r];
      }
    }
}

// ---------------- Kernel 2: fused — all-contiguous loads, wave-private regroup ----
// Per-bn block (1024), 512 thr = 8 waves, lb(512,6). Wave w = (tile T=w>>1,
// K-half h2=w&1): 8 CONTIGUOUS k loads (2x512B segments/instr — the proven pv
// shape), convert -> wave-PRIVATE LDS frag region (lgkm-only, no barrier between
// issue and use), 4 MFMAs (half-K), partial-C exchange between wave pairs.
// v loads issued right after MFMA ride under exchange+softmax. All 8 waves PV.
// k-placement (ks,g,j)=(c>>5,(c&31)>>3,c&7) identical on A and B (R8-verified
// symmetry); softmax/attn/wsp code verbatim from R18.
constexpr int AOFF  = 0;        // 8 waves x 4160 (4 ks x 1040)
constexpr int BOFF  = 33280;    // 8 ks x 1040
constexpr int WOFF  = 41600;    // wsp: 4 x 64 floats
constexpr int CXOFF = 42624;    // C-exchange: 4 tiles x 64 lanes x 16B
constexpr int SMEM4 = 46720;

__global__ __launch_bounds__(512, 6) void attn_fused_kernel(
    const float* __restrict__ qW, const float* __restrict__ kin,
    const float* __restrict__ vin, const float* __restrict__ bin,
    float* __restrict__ out, float* __restrict__ attn_out) {
  __shared__ alignas(16) long long smem_ll[SMEM4 / 8];
  char* sm = reinterpret_cast<char*>(smem_ll);
  float* wsp = reinterpret_cast<float*>(sm + WOFF);
  const int tid = threadIdx.x;
  const int bn  = blockIdx.x;
  const int wid = tid >> 6;          // 0..7
  const int ln  = tid & 63;
  const int T   = wid >> 1;          // tile 0..3
  const int h2  = wid & 1;           // K-half

  // ---- batch: 8 contiguous k loads (wave covers rows T*16..+15, cols h2*128..+128)
  const float* kb = kin + (size_t)bn * 16384 + (size_t)(T * 16) * 256 + h2 * 128;
  float4 ka[8];
  #pragma unroll
  for (int j = 0; j < 8; ++j)
    ka[j] = *reinterpret_cast<const float4*>(kb + (size_t)(2 * j + (ln >> 5)) * 256 + (ln & 31) * 4);

  // ---- qW stage: 512 threads x 1 float4 = full 8x256 row
  const float4* qw4 = reinterpret_cast<const float4*>(qW) + (size_t)bn * 512;
  float4 qv = qw4[tid];

  // ---- zero-fill unwritten B slots (cols 8-15): 256 slots, first 256 threads
  if (tid < 256) {
    const int ks = tid >> 5, slot = 32 + (tid & 31);
    *reinterpret_cast<uint4*>(sm + BOFF + ks * 1040 + slot * 16) =
        make_uint4(0u, 0u, 0u, 0u);
  }
  // ---- qW -> B-hi frags (R18-verified placement, 512 threads)
  {
    const int hh = tid >> 6, equad = tid & 63;
    const int ks = equad >> 3, g = (equad >> 1) & 3, j0 = (equad & 1) * 4;
    const int base = BOFF + ks * 1040 + (hh * 4 + g) * 16 + j0 * 2;
    unsigned short h0 = bf16rn(qv.x), h1 = bf16rn(qv.y),
                   h2b = bf16rn(qv.z), h3 = bf16rn(qv.w);
    *reinterpret_cast<uint2*>(sm + base) =
        make_uint2((unsigned)h0 | ((unsigned)h1 << 16),
                   (unsigned)h2b | ((unsigned)h3 << 16));
  }
  // ---- k convert + wave-private frag writes
  {
    char* aw = sm + AOFF + wid * 4160;
    const int kl = (ln & 31) >> 3;          // local ks 0..3
    const int g  = (ln & 7) >> 1;
    const int j0 = (ln & 1) * 4;
    #pragma unroll
    for (int j = 0; j < 8; ++j) {
      const int slot = (2 * j + (ln >> 5)) * 4 + g;
      unsigned short h0 = bf16rn(ka[j].x), h1 = bf16rn(ka[j].y),
                     h2b = bf16rn(ka[j].z), h3 = bf16rn(ka[j].w);
      *reinterpret_cast<uint2*>(aw + kl * 1040 + slot * 16 + j0 * 2) =
          make_uint2((unsigned)h0 | ((unsigned)h1 << 16),
                     (unsigned)h2b | ((unsigned)h3 << 16));
    }
  }
  __syncthreads();   // B1: B-frags (cross-wave) + own A-frags visible

  // ---- MFMA over K-half (4 ksteps), tile T
  const int slot_r = (ln & 15) * 4 + (ln >> 4);
  const char* pa = sm + AOFF + wid * 4160 + slot_r * 16;
  const char* pb = sm + BOFF + slot_r * 16;
  f32x4 acc = {0.f, 0.f, 0.f, 0.f};
  #pragma unroll
  for (int kl = 0; kl < 4; ++kl) {
    bf16x8 aH = *reinterpret_cast<const bf16x8*>(pa + kl * 1040);
    bf16x8 bH = *reinterpret_cast<const bf16x8*>(pb + (h2 * 4 + kl) * 1040);
    acc = __builtin_amdgcn_mfma_f32_16x16x32_bf16(aH, bH, acc, 0, 0, 0);
  }

  // ---- issue v loads now (contiguous rows wid+8i); ride under exchange+softmax
  const float4* v4 = reinterpret_cast<const float4*>(vin) + (size_t)bn * 4096;
  float4 vv[8];
  #pragma unroll
  for (int i = 0; i < 8; ++i) vv[i] = v4[(size_t)(wid + 8 * i) * 64 + ln];

  // ---- partial-C exchange: h2=1 writes, h2=0 adds
  if (h2) {
    *reinterpret_cast<f32x4*>(sm + CXOFF + T * 1024 + ln * 16) = acc;
  }
  __syncthreads();   // B2: exchange visible

  if (!h2) {
    f32x4 o = *reinterpret_cast<const f32x4*>(sm + CXOFF + T * 1024 + ln * 16);
    acc[0] += o[0]; acc[1] += o[1]; acc[2] += o[2]; acc[3] += o[3];

    // ---- softmax on C-frags (R14-R18-verified, wid -> T)
    const float bias = bin[ln & 7];
    const int col = ln & 15;
    const bool valid = col < 8;
    float x0 = acc[0] + bias, x1 = acc[1] + bias, x2 = acc[2] + bias, x3 = acc[3] + bias;
    float m = valid ? fmaxf(fmaxf(x0, x1), fmaxf(x2, x3)) : -1e30f;
    m = fmaxf(m, __shfl_xor(m, 1, 64));
    m = fmaxf(m, __shfl_xor(m, 2, 64));
    m = fmaxf(m, __shfl_xor(m, 4, 64));
    m = fmaxf(m, __shfl_xor(m, 16, 64));
    float e0 = valid ? expf(x0 - m) : 0.f;
    float e1 = valid ? expf(x1 - m) : 0.f;
    float e2 = valid ? expf(x2 - m) : 0.f;
    float e3 = valid ? expf(x3 - m) : 0.f;
    float s = e0 + e1 + e2 + e3;
    s += __shfl_xor(s, 1, 64);
    s += __shfl_xor(s, 2, 64);
    s += __shfl_xor(s, 4, 64);
    s += __shfl_xor(s, 16, 64);
    float inv = 1.f / s;
    float p0 = e0 * inv, p1 = e1 * inv, p2 = e2 * inv, p3 = e3 * inv;
    if (valid) {
      size_t base = (size_t)bn * 512 + (size_t)(T * 16 + (ln >> 4) * 4) * 8 + col;
      attn_out[base]      = p0;
      attn_out[base + 8]  = p1;
      attn_out[base + 16] = p2;
      attn_out[base + 24] = p3;
    }
    // wsum partial (verified mapping)
    p0 += __shfl_xor(p0, 32, 64);
    p1 += __shfl_xor(p1, 32, 64);
    p2 += __shfl_xor(p2, 32, 64);
    p3 += __shfl_xor(p3, 32, 64);
    if (ln < 32 && (ln & 15) < 8) {
      const int rb = (ln >> 4) * 4;
      const int c8 = ln & 7;
      float* w = wsp + T * 64;
      w[(rb + 0) * 8 + c8] = p0;
      w[(rb + 1) * 8 + c8] = p1;
      w[(rb + 2) * 8 + c8] = p2;
      w[(rb + 3) * 8 + c8] = p3;
    }
  }
  __syncthreads();   // B3: wsp complete; A-frag area dead below

  // ---- PV: all 8 waves, rows wid+8i (contiguous); wsum via broadcast LDS reads
  float4 av = make_float4(0.f, 0.f, 0.f, 0.f);
  #pragma unroll
  for (int i = 0; i < 8; ++i) {
    const int r = wid + 8 * i;
    float w = wsp[r] + wsp[64 + r] + wsp[128 + r] + wsp[192 + r];
    av.x += w * vv[i].x; av.y += w * vv[i].y;
    av.z += w * vv[i].z; av.w += w * vv[i].w;
  }
  float* s_red = reinterpret_cast<float*>(sm);   // [8][260] alias on dead A area
  *reinterpret_cast<float4*>(&s_red[wid * 260 + (ln << 2)]) = av;
  __syncthreads();   // B4: s_red complete

  if (tid < 256) {
    float o = 0.f;
    #pragma unroll
    for (int g = 0; g < 8; ++g) o += s_red[g * 260 + tid];
    out[(size_t)bn * D + tid] = o;
  }
}

}  // namespace

extern "C" void kernel_launch(void* const* d_in, const int* in_sizes, int n_in,
                              void* d_out, int out_size, void* d_ws, size_t ws_size,
                              hipStream_t stream) {
  const float* q = (const float*)d_in[0];   // (8,128,1,256)
  const float* k = (const float*)d_in[1];   // (8,128,64,256)
  const float* v = (const float*)d_in[2];   // (8,128,64,256)
  const float* W = (const float*)d_in[3];   // (8,256,256)
  const float* b = (const float*)d_in[4];   // (8,)

  float* out  = (float*)d_out;              // output: 262144 f32
  float* attn = out + 262144;               // attn:   524288 f32
  char*  ws   = (char*)d_ws;
  float* qWbuf = (float*)(ws + OFF_QW);     // 8 MiB f32 qW

  hipLaunchKernelGGL(prep_kernel,       dim3(384),  dim3(256), 0, stream, q, W, ws);
  hipLaunchKernelGGL(qw_mfma_kernel,    dim3(256),  dim3(256), 0, stream, ws, qWbuf);
  hipLaunchKernelGGL(attn_fused_kernel, dim3(1024), dim3(512), 0, stream,
                     qWbuf, k, v, b, out, attn);
}

// Round 20
// 43.032 us; speedup vs baseline: 2.8287x; 1.0250x over previous
//
#include <hip/hip_runtime.h>
#include <math.h>

namespace {

constexpr int D = 256;
constexpr int H = 8;

typedef __attribute__((ext_vector_type(8))) short bf16x8;
typedef __attribute__((ext_vector_type(4))) float f32x4;

__device__ inline unsigned short bf16rn(float x) {
  unsigned u = __builtin_bit_cast(unsigned, x);
  u += 0x7fffu + ((u >> 16) & 1u);
  return (unsigned short)(u >> 16);
}
__device__ inline float bf16tof(unsigned short b) {
  return __builtin_bit_cast(float, (unsigned)b << 16);
}

// Unsinkable 16B load: volatile asm stays in program order; result must live in VGPRs.
__device__ inline float4 gl4(const float* p) {
  float4 r;
  asm volatile("global_load_dwordx4 %0, %1, off" : "=v"(r) : "v"(p) : "memory");
  return r;
}
#define VMCNT_WAIT(n)                                            \
  asm volatile("s_waitcnt vmcnt(" #n ")" ::: "memory");          \
  __builtin_amdgcn_sched_barrier(0)

// workspace byte offsets
constexpr size_t OFF_QW  = 0;                          // 8 MiB f32 qW
constexpr size_t OFF_WFH = (size_t)8 << 20;            // 1 MiB W-frag hi
constexpr size_t OFF_WFL = (size_t)9 << 20;            // 1 MiB W-frag lo
constexpr size_t OFF_QFH = (size_t)10 << 20;           // 512 KiB q-frag hi
constexpr size_t OFF_QFL = ((size_t)10 << 20) + ((size_t)512 << 10);

// ---------------- Kernel 0: prep — bf16 hi/lo fragments of q and W ----------------
// (byte-identical to R11-R19 — verified)
__global__ __launch_bounds__(256) void prep_kernel(
    const float* __restrict__ q, const float* __restrict__ W,
    char* __restrict__ ws) {
  const int gid = blockIdx.x * 256 + threadIdx.x;
  float e[8];
  char *hi_base, *lo_base;
  size_t outoff;
  if (gid < 65536) {          // blocks 0..255: W part
    const int l = gid & 63, ks = (gid >> 6) & 7, he = gid >> 9;
    const int h = he >> 4, et = he & 15;
    const int d0 = ks * 32 + ((l >> 4) << 3);
    const int ecol = et * 16 + (l & 15);
    const float* src = W + (size_t)h * 65536 + (size_t)d0 * 256 + ecol;
    #pragma unroll
    for (int j = 0; j < 8; ++j) e[j] = src[j * 256];
    hi_base = ws + OFF_WFH; lo_base = ws + OFF_WFL;
    outoff = (size_t)gid * 16;
  } else {                    // blocks 256..383: q part
    const int t = gid - 65536;
    const int l = t & 63, ks = (t >> 6) & 7, bt = t >> 9;
    const int row = bt * 16 + (l & 15);
    const int d0 = ks * 32 + ((l >> 4) << 3);
    const float4* src = reinterpret_cast<const float4*>(q + (size_t)row * 256 + d0);
    float4 a = src[0], b = src[1];
    e[0] = a.x; e[1] = a.y; e[2] = a.z; e[3] = a.w;
    e[4] = b.x; e[5] = b.y; e[6] = b.z; e[7] = b.w;
    hi_base = ws + OFF_QFH; lo_base = ws + OFF_QFL;
    outoff = (size_t)t * 16;
  }
  unsigned hw[4], lw[4];
  #pragma unroll
  for (int p = 0; p < 4; ++p) {
    unsigned short h0 = bf16rn(e[2 * p]), h1 = bf16rn(e[2 * p + 1]);
    unsigned short l0 = bf16rn(e[2 * p] - bf16tof(h0));
    unsigned short l1 = bf16rn(e[2 * p + 1] - bf16tof(h1));
    hw[p] = (unsigned)h0 | ((unsigned)h1 << 16);
    lw[p] = (unsigned)l0 | ((unsigned)l1 << 16);
  }
  *reinterpret_cast<uint4*>(hi_base + outoff) = make_uint4(hw[0], hw[1], hw[2], hw[3]);
  *reinterpret_cast<uint4*>(lo_base + outoff) = make_uint4(lw[0], lw[1], lw[2], lw[3]);
}

// ---------------- Kernel 1: qW via split-bf16 MFMA ----------------
// (byte-identical to R11-R19 — verified; keeps f32-grade qW)
__global__ __launch_bounds__(256) void qw_mfma_kernel(
    const char* __restrict__ ws_in, float* __restrict__ qW) {
  const int tid = threadIdx.x;
  const int w   = blockIdx.x * 4 + (tid >> 6);
  const int l   = tid & 63;
  const int bng = w >> 5;
  const int heg = w & 31;
  const char* qfh = ws_in + OFF_QFH;
  const char* qfl = ws_in + OFF_QFL;
  const char* wfh = ws_in + OFF_WFH;
  const char* wfl = ws_in + OFF_WFL;

  f32x4 acc[2][4];
  #pragma unroll
  for (int i = 0; i < 2; ++i)
    #pragma unroll
    for (int j = 0; j < 4; ++j) acc[i][j] = {0.f, 0.f, 0.f, 0.f};

  #pragma unroll 2
  for (int ks = 0; ks < 8; ++ks) {
    bf16x8 aH[2], aL[2], bH[4], bL[4];
    #pragma unroll
    for (int i = 0; i < 2; ++i) {
      const size_t off = ((size_t)((bng * 2 + i) * 8 + ks) * 64 + l) * 16;
      aH[i] = *reinterpret_cast<const bf16x8*>(qfh + off);
      aL[i] = *reinterpret_cast<const bf16x8*>(qfl + off);
    }
    #pragma unroll
    for (int j = 0; j < 4; ++j) {
      const size_t off = ((size_t)((heg * 4 + j) * 8 + ks) * 64 + l) * 16;
      bH[j] = *reinterpret_cast<const bf16x8*>(wfh + off);
      bL[j] = *reinterpret_cast<const bf16x8*>(wfl + off);
    }
    #pragma unroll
    for (int i = 0; i < 2; ++i)
      #pragma unroll
      for (int j = 0; j < 4; ++j) {
        acc[i][j] = __builtin_amdgcn_mfma_f32_16x16x32_bf16(aH[i], bH[j], acc[i][j], 0, 0, 0);
        acc[i][j] = __builtin_amdgcn_mfma_f32_16x16x32_bf16(aH[i], bL[j], acc[i][j], 0, 0, 0);
        acc[i][j] = __builtin_amdgcn_mfma_f32_16x16x32_bf16(aL[i], bH[j], acc[i][j], 0, 0, 0);
      }
  }

  const int rbase = (l >> 4) * 4;
  const int col   = l & 15;
  #pragma unroll
  for (int i = 0; i < 2; ++i)
    #pragma unroll
    for (int j = 0; j < 4; ++j) {
      const size_t cidx = (size_t)(heg * 4 + j) * 16 + col;
      #pragma unroll
      for (int r = 0; r < 4; ++r) {
        const int bn = (bng * 2 + i) * 16 + rbase + r;
        qW[(size_t)bn * 2048 + cidx] = acc[i][j][r];
      }
    }
}

// ---------------- Kernel 2: fused — R14 skeleton + asm load bursts, counted vmcnt --
// Per-bn block (1024), 256 thr = 4 waves, lb(256,2) -> ~180-VGPR budget, 2 blk/CU.
// ALL 34 loads (16 ka + 2 qW + 16 v) issued at t=0 via volatile-asm
// global_load_dwordx4 (unsinkable, stay live in VGPRs). vmcnt(16): ka+qW done,
// 16 v loads REMAIN IN FLIGHT across both barriers (AITER counted-wait pattern);
// vmcnt(0) only before PV. Numerics/layout byte-identical to R14 (verified).
constexpr int FB2   = 0;
constexpr int WSP2  = 8320;
constexpr int SMEM3 = 9344;

__global__ __launch_bounds__(256, 2) void attn_fused_kernel(
    const float* __restrict__ qW, const float* __restrict__ kin,
    const float* __restrict__ vin, const float* __restrict__ bin,
    float* __restrict__ out, float* __restrict__ attn_out) {
  __shared__ alignas(16) long long smem_ll[SMEM3 / 8];
  char* sm = reinterpret_cast<char*>(smem_ll);
  float* wsp = reinterpret_cast<float*>(sm + WSP2);   // flat [4*64]
  const int tid = threadIdx.x;
  const int bn  = blockIdx.x;
  const int wid = tid >> 6;
  const int ln  = tid & 63;

  // ---- burst 1: A-direct k-frag loads (16), issue order matters for vmcnt
  const float* arow = kin + (size_t)bn * 16384 +
                      (size_t)(wid * 16 + (ln & 15)) * 256 + ((ln >> 4) << 3);
  float4 ka[16];
  #pragma unroll
  for (int ks = 0; ks < 8; ++ks) {
    ka[2 * ks]     = gl4(arow + ks * 32);
    ka[2 * ks + 1] = gl4(arow + ks * 32 + 4);
  }
  // ---- burst 2: qW loads (2)
  const float* qwp = qW + (size_t)bn * 2048;
  float4 qv0 = gl4(qwp + tid * 4);
  float4 qv1 = gl4(qwp + 1024 + tid * 4);
  // ---- burst 3: v loads (16) — consumed last, stay in flight across barriers
  const float* vp = vin + (size_t)bn * 16384;
  float4 vv[16];
  #pragma unroll
  for (int i = 0; i < 16; ++i)
    vv[i] = gl4(vp + (size_t)(wid + 4 * i) * 256 + ln * 4);

  // ---- zero-fill unwritten B slots (cols 8-15) — no load dependency
  {
    const int ks = tid >> 5, slot = 32 + (tid & 31);
    *reinterpret_cast<uint4*>(sm + FB2 + ks * 1040 + slot * 16) =
        make_uint4(0u, 0u, 0u, 0u);
  }

  VMCNT_WAIT(16);   // ka (issued first) + qv complete; 16 v loads still in flight

  // ---- qW -> B-hi frags (R13/R14-verified placement)
  #pragma unroll
  for (int i = 0; i < 2; ++i) {
    int p = tid + 256 * i;
    int hh = p >> 6, equad = p & 63;
    int ks = equad >> 3, g = (equad >> 1) & 3, j0 = (equad & 1) * 4;
    int base = FB2 + ks * 1040 + (hh * 4 + g) * 16 + j0 * 2;
    float4 qv = i == 0 ? qv0 : qv1;
    unsigned short h0 = bf16rn(qv.x), h1 = bf16rn(qv.y),
                   h2 = bf16rn(qv.z), h3 = bf16rn(qv.w);
    *reinterpret_cast<uint2*>(sm + base) =
        make_uint2((unsigned)h0 | ((unsigned)h1 << 16),
                   (unsigned)h2 | ((unsigned)h3 << 16));
  }
  __syncthreads();

  // ---- MFMA over full K=256, tile T = wid (converts ka in registers)
  const int slot_r = (ln & 15) * 4 + (ln >> 4);
  const char* pbH = sm + FB2 + slot_r * 16;
  f32x4 acc = {0.f, 0.f, 0.f, 0.f};
  #pragma unroll
  for (int ks = 0; ks < 8; ++ks) {
    const float4 a0 = ka[2 * ks], a1 = ka[2 * ks + 1];
    bf16x8 aH;
    aH[0] = (short)bf16rn(a0.x); aH[1] = (short)bf16rn(a0.y);
    aH[2] = (short)bf16rn(a0.z); aH[3] = (short)bf16rn(a0.w);
    aH[4] = (short)bf16rn(a1.x); aH[5] = (short)bf16rn(a1.y);
    aH[6] = (short)bf16rn(a1.z); aH[7] = (short)bf16rn(a1.w);
    bf16x8 bH = *reinterpret_cast<const bf16x8*>(pbH + ks * 1040);
    acc = __builtin_amdgcn_mfma_f32_16x16x32_bf16(aH, bH, acc, 0, 0, 0);
  }

  // ---- softmax on C-frags (chunk = 2*wid + (ln>=32); R14-verified reduce)
  const float bias = bin[ln & 7];
  const int col = ln & 15;
  const bool valid = col < 8;
  float x0 = acc[0] + bias, x1 = acc[1] + bias, x2 = acc[2] + bias, x3 = acc[3] + bias;
  float m = valid ? fmaxf(fmaxf(x0, x1), fmaxf(x2, x3)) : -1e30f;
  m = fmaxf(m, __shfl_xor(m, 1, 64));
  m = fmaxf(m, __shfl_xor(m, 2, 64));
  m = fmaxf(m, __shfl_xor(m, 4, 64));
  m = fmaxf(m, __shfl_xor(m, 16, 64));
  float e0 = valid ? expf(x0 - m) : 0.f;
  float e1 = valid ? expf(x1 - m) : 0.f;
  float e2 = valid ? expf(x2 - m) : 0.f;
  float e3 = valid ? expf(x3 - m) : 0.f;
  float s = e0 + e1 + e2 + e3;
  s += __shfl_xor(s, 1, 64);
  s += __shfl_xor(s, 2, 64);
  s += __shfl_xor(s, 4, 64);
  s += __shfl_xor(s, 16, 64);
  float inv = 1.f / s;
  float p0 = e0 * inv, p1 = e1 * inv, p2 = e2 * inv, p3 = e3 * inv;
  if (valid) {
    size_t base = (size_t)bn * 512 + (size_t)(wid * 16 + (ln >> 4) * 4) * 8 + col;
    attn_out[base]      = p0;
    attn_out[base + 8]  = p1;
    attn_out[base + 16] = p2;
    attn_out[base + 24] = p3;
  }
  // wsum partial: pos=(row&7)*8+col, chunk-pair sum via xor-32; one writer/pos.
  p0 += __shfl_xor(p0, 32, 64);
  p1 += __shfl_xor(p1, 32, 64);
  p2 += __shfl_xor(p2, 32, 64);
  p3 += __shfl_xor(p3, 32, 64);
  if (ln < 32 && (ln & 15) < 8) {
    const int rb = (ln >> 4) * 4;
    const int c8 = ln & 7;
    float* w = wsp + wid * 64;
    w[(rb + 0) * 8 + c8] = p0;
    w[(rb + 1) * 8 + c8] = p1;
    w[(rb + 2) * 8 + c8] = p2;
    w[(rb + 3) * 8 + c8] = p3;
  }
  __syncthreads();

  VMCNT_WAIT(0);    // v loads complete (hidden under everything above)

  // ---- PV from vv; wsum via broadcast LDS reads
  float4 av = make_float4(0.f, 0.f, 0.f, 0.f);
  #pragma unroll
  for (int i = 0; i < 16; ++i) {
    const int r = wid + 4 * i;
    float w = wsp[r] + wsp[64 + r] + wsp[128 + r] + wsp[192 + r];
    av.x += w * vv[i].x; av.y += w * vv[i].y;
    av.z += w * vv[i].z; av.w += w * vv[i].w;
  }
  float* s_red = reinterpret_cast<float*>(sm);   // [4][260] alias on dead B-frag area
  *reinterpret_cast<float4*>(&s_red[wid * 260 + (ln << 2)]) = av;
  __syncthreads();

  out[(size_t)bn * D + tid] =
      s_red[tid] + s_red[260 + tid] + s_red[520 + tid] + s_red[780 + tid];
}

}  // namespace

extern "C" void kernel_launch(void* const* d_in, const int* in_sizes, int n_in,
                              void* d_out, int out_size, void* d_ws, size_t ws_size,
                              hipStream_t stream) {
  const float* q = (const float*)d_in[0];   // (8,128,1,256)
  const float* k = (const float*)d_in[1];   // (8,128,64,256)
  const float* v = (const float*)d_in[2];   // (8,128,64,256)
  const float* W = (const float*)d_in[3];   // (8,256,256)
  const float* b = (const float*)d_in[4];   // (8,)

  float* out  = (float*)d_out;              // output: 262144 f32
  float* attn = out + 262144;               // attn:   524288 f32
  char*  ws   = (char*)d_ws;
  float* qWbuf = (float*)(ws + OFF_QW);     // 8 MiB f32 qW

  hipLaunchKernelGGL(prep_kernel,       dim3(384),  dim3(256), 0, stream, q, W, ws);
  hipLaunchKernelGGL(qw_mfma_kernel,    dim3(256),  dim3(256), 0, stream, ws, qWbuf);
  hipLaunchKernelGGL(attn_fused_kernel, dim3(1024), dim3(256), 0, stream,
                     qWbuf, k, v, b, out, attn);
}

// Round 21
// 41.277 us; speedup vs baseline: 2.9489x; 1.0425x over previous
//
#include <hip/hip_runtime.h>
#include <math.h>

namespace {

constexpr int D = 256;
constexpr int H = 8;

typedef __attribute__((ext_vector_type(8))) short bf16x8;
typedef __attribute__((ext_vector_type(4))) float f32x4;

__device__ inline unsigned short bf16rn(float x) {
  unsigned u = __builtin_bit_cast(unsigned, x);
  u += 0x7fffu + ((u >> 16) & 1u);
  return (unsigned short)(u >> 16);
}
__device__ inline float bf16tof(unsigned short b) {
  return __builtin_bit_cast(float, (unsigned)b << 16);
}

// workspace byte offsets
constexpr size_t OFF_QWB = 0;                          // 2 MiB bf16 qW (row-major [bn][2048])
constexpr size_t OFF_WFH = (size_t)8 << 20;            // 1 MiB W-frag hi
constexpr size_t OFF_WFL = (size_t)9 << 20;            // 1 MiB W-frag lo
constexpr size_t OFF_QFH = (size_t)10 << 20;           // 512 KiB q-frag hi
constexpr size_t OFF_QFL = ((size_t)10 << 20) + ((size_t)512 << 10);

// ---------------- Kernel 0: prep — bf16 hi/lo fragments of q and W ----------------
// (byte-identical to R11-R20 — verified)
__global__ __launch_bounds__(256) void prep_kernel(
    const float* __restrict__ q, const float* __restrict__ W,
    char* __restrict__ ws) {
  const int gid = blockIdx.x * 256 + threadIdx.x;
  float e[8];
  char *hi_base, *lo_base;
  size_t outoff;
  if (gid < 65536) {          // blocks 0..255: W part
    const int l = gid & 63, ks = (gid >> 6) & 7, he = gid >> 9;
    const int h = he >> 4, et = he & 15;
    const int d0 = ks * 32 + ((l >> 4) << 3);
    const int ecol = et * 16 + (l & 15);
    const float* src = W + (size_t)h * 65536 + (size_t)d0 * 256 + ecol;
    #pragma unroll
    for (int j = 0; j < 8; ++j) e[j] = src[j * 256];
    hi_base = ws + OFF_WFH; lo_base = ws + OFF_WFL;
    outoff = (size_t)gid * 16;
  } else {                    // blocks 256..383: q part
    const int t = gid - 65536;
    const int l = t & 63, ks = (t >> 6) & 7, bt = t >> 9;
    const int row = bt * 16 + (l & 15);
    const int d0 = ks * 32 + ((l >> 4) << 3);
    const float4* src = reinterpret_cast<const float4*>(q + (size_t)row * 256 + d0);
    float4 a = src[0], b = src[1];
    e[0] = a.x; e[1] = a.y; e[2] = a.z; e[3] = a.w;
    e[4] = b.x; e[5] = b.y; e[6] = b.z; e[7] = b.w;
    hi_base = ws + OFF_QFH; lo_base = ws + OFF_QFL;
    outoff = (size_t)t * 16;
  }
  unsigned hw[4], lw[4];
  #pragma unroll
  for (int p = 0; p < 4; ++p) {
    unsigned short h0 = bf16rn(e[2 * p]), h1 = bf16rn(e[2 * p + 1]);
    unsigned short l0 = bf16rn(e[2 * p] - bf16tof(h0));
    unsigned short l1 = bf16rn(e[2 * p + 1] - bf16tof(h1));
    hw[p] = (unsigned)h0 | ((unsigned)h1 << 16);
    lw[p] = (unsigned)l0 | ((unsigned)l1 << 16);
  }
  *reinterpret_cast<uint4*>(hi_base + outoff) = make_uint4(hw[0], hw[1], hw[2], hw[3]);
  *reinterpret_cast<uint4*>(lo_base + outoff) = make_uint4(lw[0], lw[1], lw[2], lw[3]);
}

// ---------------- Kernel 1: qW via split-bf16 MFMA -> bf16 qW output ----------------
// Same verified MFMA core as R11-R20; DELTA: emit bf16 (hi-round of f32 acc) into
// row-major bf16 [bn][2048] — numerically identical to fused's old convert, halves
// the qW round-trip (8+8 MB -> 2+2 MB).
__global__ __launch_bounds__(256) void qw_mfma_kernel(
    const char* __restrict__ ws_in, unsigned short* __restrict__ qWb) {
  const int tid = threadIdx.x;
  const int w   = blockIdx.x * 4 + (tid >> 6);
  const int l   = tid & 63;
  const int bng = w >> 5;
  const int heg = w & 31;
  const char* qfh = ws_in + OFF_QFH;
  const char* qfl = ws_in + OFF_QFL;
  const char* wfh = ws_in + OFF_WFH;
  const char* wfl = ws_in + OFF_WFL;

  f32x4 acc[2][4];
  #pragma unroll
  for (int i = 0; i < 2; ++i)
    #pragma unroll
    for (int j = 0; j < 4; ++j) acc[i][j] = {0.f, 0.f, 0.f, 0.f};

  #pragma unroll 2
  for (int ks = 0; ks < 8; ++ks) {
    bf16x8 aH[2], aL[2], bH[4], bL[4];
    #pragma unroll
    for (int i = 0; i < 2; ++i) {
      const size_t off = ((size_t)((bng * 2 + i) * 8 + ks) * 64 + l) * 16;
      aH[i] = *reinterpret_cast<const bf16x8*>(qfh + off);
      aL[i] = *reinterpret_cast<const bf16x8*>(qfl + off);
    }
    #pragma unroll
    for (int j = 0; j < 4; ++j) {
      const size_t off = ((size_t)((heg * 4 + j) * 8 + ks) * 64 + l) * 16;
      bH[j] = *reinterpret_cast<const bf16x8*>(wfh + off);
      bL[j] = *reinterpret_cast<const bf16x8*>(wfl + off);
    }
    #pragma unroll
    for (int i = 0; i < 2; ++i)
      #pragma unroll
      for (int j = 0; j < 4; ++j) {
        acc[i][j] = __builtin_amdgcn_mfma_f32_16x16x32_bf16(aH[i], bH[j], acc[i][j], 0, 0, 0);
        acc[i][j] = __builtin_amdgcn_mfma_f32_16x16x32_bf16(aH[i], bL[j], acc[i][j], 0, 0, 0);
        acc[i][j] = __builtin_amdgcn_mfma_f32_16x16x32_bf16(aL[i], bH[j], acc[i][j], 0, 0, 0);
      }
  }

  const int rbase = (l >> 4) * 4;
  const int col   = l & 15;
  #pragma unroll
  for (int i = 0; i < 2; ++i)
    #pragma unroll
    for (int j = 0; j < 4; ++j) {
      const size_t cidx = (size_t)(heg * 4 + j) * 16 + col;
      #pragma unroll
      for (int r = 0; r < 4; ++r) {
        const int bn = (bng * 2 + i) * 16 + rbase + r;
        qWb[(size_t)bn * 2048 + cidx] = bf16rn(acc[i][j][r]);
      }
    }
}

// ---------------- Kernel 2: fused scores+softmax+PV (R14 skeleton, bf16 qW in) ----
// Per-bn block (1024), 256 thr = 4 waves, lb(256,4) — the best-measured structure
// (R14, 42.2 us). DELTA vs R14: qW arrives as bf16 row-major; one uint4 load per
// thread (8 bf16 = elements 8*tid..+8) feeds the SAME placement formulas with
// p = 2*tid and 2*tid+1 (uint2 halves of the uint4) — no convert needed.
constexpr int FB2   = 0;
constexpr int WSP2  = 8320;
constexpr int SMEM3 = 9344;

__global__ __launch_bounds__(256, 4) void attn_fused_kernel(
    const unsigned short* __restrict__ qWb, const float* __restrict__ kin,
    const float* __restrict__ vin, const float* __restrict__ bin,
    float* __restrict__ out, float* __restrict__ attn_out) {
  __shared__ alignas(16) long long smem_ll[SMEM3 / 8];
  char* sm = reinterpret_cast<char*>(smem_ll);
  float* wsp = reinterpret_cast<float*>(sm + WSP2);   // flat [4*64]
  const int tid = threadIdx.x;
  const int bn  = blockIdx.x;
  const int wid = tid >> 6;
  const int ln  = tid & 63;

  // ---- A-direct k-frag loads (16 independent float4; R14-verified addressing)
  const float* arow = kin + (size_t)bn * 16384 +
                      (size_t)(wid * 16 + (ln & 15)) * 256 + ((ln >> 4) << 3);
  float4 ka[16];
  #pragma unroll
  for (int ks = 0; ks < 8; ++ks) {
    ka[2 * ks]     = *reinterpret_cast<const float4*>(arow + ks * 32);
    ka[2 * ks + 1] = *reinterpret_cast<const float4*>(arow + ks * 32 + 4);
  }
  // ---- qW bf16 load: 8 bf16/thread
  uint4 qh = *reinterpret_cast<const uint4*>(qWb + (size_t)bn * 2048 + tid * 8);

  // ---- zero-fill unwritten B slots (cols 8-15)
  {
    const int ks = tid >> 5, slot = 32 + (tid & 31);
    *reinterpret_cast<uint4*>(sm + FB2 + ks * 1040 + slot * 16) =
        make_uint4(0u, 0u, 0u, 0u);
  }
  // ---- B-hi frag placement (verified formulas); p = 2*tid, 2*tid+1
  #pragma unroll
  for (int i = 0; i < 2; ++i) {
    const int p = 2 * tid + i;
    const int hh = p >> 6, equad = p & 63;
    const int ks = equad >> 3, g = (equad >> 1) & 3, j0 = (equad & 1) * 4;
    const int base = FB2 + ks * 1040 + (hh * 4 + g) * 16 + j0 * 2;
    *reinterpret_cast<uint2*>(sm + base) =
        i == 0 ? make_uint2(qh.x, qh.y) : make_uint2(qh.z, qh.w);
  }
  __syncthreads();

  // ---- MFMA over full K=256, tile T = wid (converts ka in registers)
  const int slot_r = (ln & 15) * 4 + (ln >> 4);
  const char* pbH = sm + FB2 + slot_r * 16;
  f32x4 acc = {0.f, 0.f, 0.f, 0.f};
  #pragma unroll
  for (int ks = 0; ks < 8; ++ks) {
    const float4 a0 = ka[2 * ks], a1 = ka[2 * ks + 1];
    bf16x8 aH;
    aH[0] = (short)bf16rn(a0.x); aH[1] = (short)bf16rn(a0.y);
    aH[2] = (short)bf16rn(a0.z); aH[3] = (short)bf16rn(a0.w);
    aH[4] = (short)bf16rn(a1.x); aH[5] = (short)bf16rn(a1.y);
    aH[6] = (short)bf16rn(a1.z); aH[7] = (short)bf16rn(a1.w);
    bf16x8 bH = *reinterpret_cast<const bf16x8*>(pbH + ks * 1040);
    acc = __builtin_amdgcn_mfma_f32_16x16x32_bf16(aH, bH, acc, 0, 0, 0);
  }

  // ---- softmax on C-frags (R14-verified reduce)
  const float bias = bin[ln & 7];
  const int col = ln & 15;
  const bool valid = col < 8;
  float x0 = acc[0] + bias, x1 = acc[1] + bias, x2 = acc[2] + bias, x3 = acc[3] + bias;
  float m = valid ? fmaxf(fmaxf(x0, x1), fmaxf(x2, x3)) : -1e30f;
  m = fmaxf(m, __shfl_xor(m, 1, 64));
  m = fmaxf(m, __shfl_xor(m, 2, 64));
  m = fmaxf(m, __shfl_xor(m, 4, 64));
  m = fmaxf(m, __shfl_xor(m, 16, 64));
  float e0 = valid ? expf(x0 - m) : 0.f;
  float e1 = valid ? expf(x1 - m) : 0.f;
  float e2 = valid ? expf(x2 - m) : 0.f;
  float e3 = valid ? expf(x3 - m) : 0.f;
  float s = e0 + e1 + e2 + e3;
  s += __shfl_xor(s, 1, 64);
  s += __shfl_xor(s, 2, 64);
  s += __shfl_xor(s, 4, 64);
  s += __shfl_xor(s, 16, 64);
  float inv = 1.f / s;
  float p0 = e0 * inv, p1 = e1 * inv, p2 = e2 * inv, p3 = e3 * inv;
  if (valid) {
    size_t base = (size_t)bn * 512 + (size_t)(wid * 16 + (ln >> 4) * 4) * 8 + col;
    attn_out[base]      = p0;
    attn_out[base + 8]  = p1;
    attn_out[base + 16] = p2;
    attn_out[base + 24] = p3;
  }
  // wsum partial: pos=(row&7)*8+col, chunk-pair sum via xor-32; one writer/pos.
  p0 += __shfl_xor(p0, 32, 64);
  p1 += __shfl_xor(p1, 32, 64);
  p2 += __shfl_xor(p2, 32, 64);
  p3 += __shfl_xor(p3, 32, 64);
  if (ln < 32 && (ln & 15) < 8) {
    const int rb = (ln >> 4) * 4;
    const int c8 = ln & 7;
    float* w = wsp + wid * 64;
    w[(rb + 0) * 8 + c8] = p0;
    w[(rb + 1) * 8 + c8] = p1;
    w[(rb + 2) * 8 + c8] = p2;
    w[(rb + 3) * 8 + c8] = p3;
  }
  __syncthreads();

  // ---- PV: 16 independent coalesced v loads; wsum via broadcast LDS reads
  const float4* v4 = reinterpret_cast<const float4*>(vin) + (size_t)bn * 4096;
  float4 av = make_float4(0.f, 0.f, 0.f, 0.f);
  #pragma unroll
  for (int i = 0; i < 16; ++i) {
    const int r = wid + 4 * i;
    float w = wsp[r] + wsp[64 + r] + wsp[128 + r] + wsp[192 + r];
    float4 vv = v4[r * 64 + ln];
    av.x += w * vv.x; av.y += w * vv.y; av.z += w * vv.z; av.w += w * vv.w;
  }
  float* s_red = reinterpret_cast<float*>(sm);   // [4][260] alias on dead B-frag area
  *reinterpret_cast<float4*>(&s_red[wid * 260 + (ln << 2)]) = av;
  __syncthreads();

  out[(size_t)bn * D + tid] =
      s_red[tid] + s_red[260 + tid] + s_red[520 + tid] + s_red[780 + tid];
}

}  // namespace

extern "C" void kernel_launch(void* const* d_in, const int* in_sizes, int n_in,
                              void* d_out, int out_size, void* d_ws, size_t ws_size,
                              hipStream_t stream) {
  const float* q = (const float*)d_in[0];   // (8,128,1,256)
  const float* k = (const float*)d_in[1];   // (8,128,64,256)
  const float* v = (const float*)d_in[2];   // (8,128,64,256)
  const float* W = (const float*)d_in[3];   // (8,256,256)
  const float* b = (const float*)d_in[4];   // (8,)

  float* out  = (float*)d_out;              // output: 262144 f32
  float* attn = out + 262144;               // attn:   524288 f32
  char*  ws   = (char*)d_ws;
  unsigned short* qWb = (unsigned short*)(ws + OFF_QWB);  // 2 MiB bf16 qW

  hipLaunchKernelGGL(prep_kernel,       dim3(384),  dim3(256), 0, stream, q, W, ws);
  hipLaunchKernelGGL(qw_mfma_kernel,    dim3(256),  dim3(256), 0, stream, ws, qWb);
  hipLaunchKernelGGL(attn_fused_kernel, dim3(1024), dim3(256), 0, stream,
                     qWb, k, v, b, out, attn);
}